// Round 1
// baseline (238.826 us; speedup 1.0000x reference)
//
#include <hip/hip_runtime.h>
#include <math.h>

#define NTOK 8192     // B*L
#define DIM  1024     // D
#define VDIM 32       // V
#define KCODES 4096   // K

// ---------------------------------------------------------------------------
// Kernel 1: normalize codebook rows emb[K][32] -> emb_n ; also write vq_loss=0
// ---------------------------------------------------------------------------
__global__ __launch_bounds__(256) void k_embnorm(const float* __restrict__ emb,
                                                 float* __restrict__ emb_n,
                                                 float* __restrict__ loss_out) {
    int tid  = threadIdx.x;
    int lane = tid & 31;
    int row  = blockIdx.x * 8 + (tid >> 5);
    float v = emb[row * VDIM + lane];
    float ss = v * v;
    #pragma unroll
    for (int off = 16; off > 0; off >>= 1) ss += __shfl_xor(ss, off, 32);
    float inv = 1.0f / sqrtf(ss);
    emb_n[row * VDIM + lane] = v * inv;
    if (blockIdx.x == 0 && tid == 0) loss_out[0] = 0.0f;
}

// ---------------------------------------------------------------------------
// Kernel 2: hp = h @ Wp^T + bp, then L2-normalize rows -> hp_n [NTOK][32]
// Block: 256 threads, 32 tokens/block. thread: v = tid&31, tq = tid>>5,
// computes tokens {tq, tq+8, tq+16, tq+24}. LDS-staged K-chunks of 128.
// ---------------------------------------------------------------------------
__global__ __launch_bounds__(256) void k_proj_norm(const float* __restrict__ h,
                                                   const float* __restrict__ Wp,
                                                   const float* __restrict__ bp,
                                                   float* __restrict__ hp_n) {
    __shared__ __align__(16) float Wp_s[32 * 132];  // pad 128->132 (16B aligned rows)
    __shared__ __align__(16) float h_s[32 * 132];
    int tid = threadIdx.x;
    int v   = tid & 31;
    int tq  = tid >> 5;              // 0..7
    int tok0 = blockIdx.x * 32;
    float acc0 = 0.f, acc1 = 0.f, acc2 = 0.f, acc3 = 0.f;

    for (int d0 = 0; d0 < DIM; d0 += 128) {
        __syncthreads();
        #pragma unroll
        for (int q = 0; q < 4; q++) {            // 1024 float4s / 256 threads
            int f   = q * 256 + tid;
            int row = f >> 5;                    // 0..31
            int c4  = f & 31;                    // float4 col
            float4 wv = *(const float4*)(Wp + (size_t)row * DIM + d0 + c4 * 4);
            *(float4*)(Wp_s + row * 132 + c4 * 4) = wv;
            float4 hv = *(const float4*)(h + (size_t)(tok0 + row) * DIM + d0 + c4 * 4);
            *(float4*)(h_s + row * 132 + c4 * 4) = hv;
        }
        __syncthreads();
        #pragma unroll
        for (int dd = 0; dd < 32; dd++) {
            float4 w4 = *(const float4*)(Wp_s + v * 132 + dd * 4);
            float4 h0 = *(const float4*)(h_s + (tq +  0) * 132 + dd * 4);
            float4 h1 = *(const float4*)(h_s + (tq +  8) * 132 + dd * 4);
            float4 h2 = *(const float4*)(h_s + (tq + 16) * 132 + dd * 4);
            float4 h3 = *(const float4*)(h_s + (tq + 24) * 132 + dd * 4);
            acc0 = fmaf(h0.x, w4.x, acc0); acc0 = fmaf(h0.y, w4.y, acc0);
            acc0 = fmaf(h0.z, w4.z, acc0); acc0 = fmaf(h0.w, w4.w, acc0);
            acc1 = fmaf(h1.x, w4.x, acc1); acc1 = fmaf(h1.y, w4.y, acc1);
            acc1 = fmaf(h1.z, w4.z, acc1); acc1 = fmaf(h1.w, w4.w, acc1);
            acc2 = fmaf(h2.x, w4.x, acc2); acc2 = fmaf(h2.y, w4.y, acc2);
            acc2 = fmaf(h2.z, w4.z, acc2); acc2 = fmaf(h2.w, w4.w, acc2);
            acc3 = fmaf(h3.x, w4.x, acc3); acc3 = fmaf(h3.y, w4.y, acc3);
            acc3 = fmaf(h3.z, w4.z, acc3); acc3 = fmaf(h3.w, w4.w, acc3);
        }
    }
    float b = bp[v];
    acc0 += b; acc1 += b; acc2 += b; acc3 += b;
    float s0 = acc0 * acc0, s1 = acc1 * acc1, s2 = acc2 * acc2, s3 = acc3 * acc3;
    #pragma unroll
    for (int off = 16; off > 0; off >>= 1) {
        s0 += __shfl_xor(s0, off, 32);
        s1 += __shfl_xor(s1, off, 32);
        s2 += __shfl_xor(s2, off, 32);
        s3 += __shfl_xor(s3, off, 32);
    }
    hp_n[(size_t)(tok0 + tq +  0) * VDIM + v] = acc0 * (1.0f / sqrtf(s0));
    hp_n[(size_t)(tok0 + tq +  8) * VDIM + v] = acc1 * (1.0f / sqrtf(s1));
    hp_n[(size_t)(tok0 + tq + 16) * VDIM + v] = acc2 * (1.0f / sqrtf(s2));
    hp_n[(size_t)(tok0 + tq + 24) * VDIM + v] = acc3 * (1.0f / sqrtf(s3));
}

// ---------------------------------------------------------------------------
// Kernel 3: fused scores + softmax + argmax + weighted sum.
// Logits 2*s are bounded in [-2,2] -> no max subtraction needed (no overflow).
// Block: 256 threads = 16 tokens x 16 code-slices. Codes chunked 256 at a time
// through LDS (rows padded to 36 floats = 144B, keeps float4 alignment and
// only 2-way start-bank aliasing, which is free).
// ---------------------------------------------------------------------------
__global__ __launch_bounds__(256, 2) void k_vq(const float* __restrict__ hp_n,
                                               const float* __restrict__ emb_n,
                                               const float* __restrict__ mask,
                                               float* __restrict__ hv,
                                               float* __restrict__ code_out) {
    __shared__ __align__(16) float elds[256 * 36];
    int tid = threadIdx.x;
    int g   = tid & 15;          // slice
    int tl  = tid >> 4;          // local token 0..15
    int token = blockIdx.x * 16 + tl;

    float4 hp4[8];
    const float4* hrow = (const float4*)(hp_n + (size_t)token * VDIM);
    #pragma unroll
    for (int q = 0; q < 8; q++) hp4[q] = hrow[q];

    float4 av[8];
    #pragma unroll
    for (int q = 0; q < 8; q++) av[q] = make_float4(0.f, 0.f, 0.f, 0.f);
    float l = 0.0f;
    float amax = -1e30f;
    int aidx = 0;

    for (int c0 = 0; c0 < KCODES; c0 += 256) {
        __syncthreads();
        {   // stage: one 32-float row per thread
            const float4* src = (const float4*)(emb_n + (size_t)(c0 + tid) * VDIM);
            float4* dst = (float4*)(elds + tid * 36);
            #pragma unroll
            for (int q = 0; q < 8; q++) dst[q] = src[q];
        }
        __syncthreads();
        #pragma unroll 1
        for (int i = 0; i < 16; i++) {
            int cl = (i << 4) | g;                    // strided slice assignment
            const float4* e4 = (const float4*)(elds + cl * 36);
            float4 ev[8];
            #pragma unroll
            for (int q = 0; q < 8; q++) ev[q] = e4[q];
            float sx = 0.f, sy = 0.f, sz = 0.f, sw = 0.f;
            #pragma unroll
            for (int q = 0; q < 8; q++) {
                sx = fmaf(hp4[q].x, ev[q].x, sx);
                sy = fmaf(hp4[q].y, ev[q].y, sy);
                sz = fmaf(hp4[q].z, ev[q].z, sz);
                sw = fmaf(hp4[q].w, ev[q].w, sw);
            }
            float s = (sx + sy) + (sz + sw);
            if (s > amax) { amax = s; aidx = c0 + cl; }   // ascending c -> first max kept
            float p = __expf(2.0f * s);
            l += p;
            #pragma unroll
            for (int q = 0; q < 8; q++) {
                av[q].x = fmaf(p, ev[q].x, av[q].x);
                av[q].y = fmaf(p, ev[q].y, av[q].y);
                av[q].z = fmaf(p, ev[q].z, av[q].z);
                av[q].w = fmaf(p, ev[q].w, av[q].w);
            }
        }
    }

    // reduce across the 16 slice lanes (butterfly; token occupies lanes [16t,16t+15])
    #pragma unroll
    for (int off = 1; off < 16; off <<= 1) {
        l += __shfl_xor(l, off);
        #pragma unroll
        for (int q = 0; q < 8; q++) {
            av[q].x += __shfl_xor(av[q].x, off);
            av[q].y += __shfl_xor(av[q].y, off);
            av[q].z += __shfl_xor(av[q].z, off);
            av[q].w += __shfl_xor(av[q].w, off);
        }
        float am2 = __shfl_xor(amax, off);
        int   ai2 = __shfl_xor(aidx, off);
        if (am2 > amax || (am2 == amax && ai2 < aidx)) { amax = am2; aidx = ai2; }
    }

    if (g == 0) {
        bool on = (mask[token] == 1.0f);
        float inv = on ? (1.0f / l) : 0.0f;
        float* dst = hv + (size_t)token * VDIM;
        #pragma unroll
        for (int q = 0; q < 8; q++) {
            float4 o;
            o.x = av[q].x * inv; o.y = av[q].y * inv;
            o.z = av[q].z * inv; o.w = av[q].w * inv;
            ((float4*)dst)[q] = o;
        }
        code_out[token] = on ? (float)aidx : 0.0f;
    }
}

// ---------------------------------------------------------------------------
// Kernel 4: out = hv @ Wpi^T + bpi   (Wpi is [D][V], out[t][d] = sum_v hv[t][v]*Wpi[d][v])
// Block: 256 threads, 16 tokens/block; each thread covers 4 d-columns.
// ---------------------------------------------------------------------------
__global__ __launch_bounds__(256) void k_out(const float* __restrict__ hv,
                                             const float* __restrict__ Wpi,
                                             const float* __restrict__ bpi,
                                             float* __restrict__ out) {
    __shared__ __align__(16) float hv_s[16 * 32];
    int tid = threadIdx.x;
    int tok0 = blockIdx.x * 16;
    #pragma unroll
    for (int q = 0; q < 2; q++) {
        int f = q * 256 + tid;
        hv_s[f] = hv[(size_t)tok0 * VDIM + f];
    }
    __syncthreads();
    #pragma unroll 1
    for (int q = 0; q < 4; q++) {
        int d = q * 256 + tid;
        float4 w[8];
        const float4* wp4 = (const float4*)(Wpi + (size_t)d * VDIM);
        #pragma unroll
        for (int j = 0; j < 8; j++) w[j] = wp4[j];
        float bias = bpi[d];
        #pragma unroll 1
        for (int t = 0; t < 16; t++) {
            const float4* hv4 = (const float4*)(hv_s + t * 32);
            float s = bias;
            #pragma unroll
            for (int j = 0; j < 8; j++) {
                float4 hvv = hv4[j];
                s = fmaf(hvv.x, w[j].x, s);
                s = fmaf(hvv.y, w[j].y, s);
                s = fmaf(hvv.z, w[j].z, s);
                s = fmaf(hvv.w, w[j].w, s);
            }
            out[(size_t)(tok0 + t) * DIM + d] = s;
        }
    }
}

// ---------------------------------------------------------------------------
extern "C" void kernel_launch(void* const* d_in, const int* in_sizes, int n_in,
                              void* d_out, int out_size, void* d_ws, size_t ws_size,
                              hipStream_t stream) {
    const float* h    = (const float*)d_in[0];
    const float* mask = (const float*)d_in[1];
    const float* Wp   = (const float*)d_in[2];
    const float* bp   = (const float*)d_in[3];
    const float* Wpi  = (const float*)d_in[4];
    const float* bpi  = (const float*)d_in[5];
    const float* emb  = (const float*)d_in[6];
    float* out = (float*)d_out;

    // workspace layout (floats): emb_n[4096*32] | hp_n[8192*32] | hv[8192*32]
    float* emb_n = (float*)d_ws;
    float* hp_n  = emb_n + (size_t)KCODES * VDIM;
    float* hv    = hp_n  + (size_t)NTOK * VDIM;

    float* code_out = out + (size_t)NTOK * DIM;   // 8388608
    float* loss_out = code_out + NTOK;            // 8396800

    hipLaunchKernelGGL(k_embnorm,   dim3(KCODES / 8),  dim3(256), 0, stream, emb, emb_n, loss_out);
    hipLaunchKernelGGL(k_proj_norm, dim3(NTOK / 32),   dim3(256), 0, stream, h, Wp, bp, hp_n);
    hipLaunchKernelGGL(k_vq,        dim3(NTOK / 16),   dim3(256), 0, stream, hp_n, emb_n, mask, hv, code_out);
    hipLaunchKernelGGL(k_out,       dim3(NTOK / 16),   dim3(256), 0, stream, hv, Wpi, bpi, out);
}

// Round 2
// 173.328 us; speedup vs baseline: 1.3779x; 1.3779x over previous
//
#include <hip/hip_runtime.h>
#include <math.h>

#define NTOK 8192     // B*L
#define DIM  1024     // D
#define VDIM 32       // V
#define KCODES 4096   // K

typedef __attribute__((ext_vector_type(8))) short short8;
typedef __attribute__((ext_vector_type(4))) float f32x4;

#define MFMA16(A,B,C) __builtin_amdgcn_mfma_f32_16x16x32_bf16(A, B, C, 0, 0, 0)

__device__ __forceinline__ unsigned short f2bf(float x) {
    unsigned u = __builtin_bit_cast(unsigned, x);
    u += 0x7FFF + ((u >> 16) & 1);              // RTNE (finite inputs only)
    return (unsigned short)(u >> 16);
}
__device__ __forceinline__ float bf2f(unsigned short b) {
    unsigned u = ((unsigned)b) << 16;
    return __builtin_bit_cast(float, u);
}

// ---------------------------------------------------------------------------
// ws layout (u16 units)
// ---------------------------------------------------------------------------
#define OFS_E_HI   0
#define OFS_E_LO   131072
#define OFS_ET_HI  262144
#define OFS_ET_LO  393216
#define OFS_WP_HI  524288
#define OFS_WP_LO  557056
#define OFS_WPI_HI 589824
#define OFS_WPI_LO 622592
#define OFS_HP_HI  655360
#define OFS_HP_LO  917504

// ---------------------------------------------------------------------------
// k_prep: normalize emb -> E_hi/lo [4096][32] + Et_hi/lo [32][4096];
// split Wp [32][1024] and Wpi [1024][32] into bf16 hi/lo; vq_loss = 0.
// ---------------------------------------------------------------------------
__global__ __launch_bounds__(256) void k_prep(const float* __restrict__ emb,
                                              const float* __restrict__ Wp,
                                              const float* __restrict__ Wpi,
                                              unsigned short* __restrict__ W,
                                              float* __restrict__ loss_out) {
    int bid = blockIdx.x, tid = threadIdx.x;
    if (bid < 512) {                       // emb: 8 rows/block, 32 lanes/row
        int row = bid * 8 + (tid >> 5);
        int v   = tid & 31;
        float x = emb[row * VDIM + v];
        float ss = x * x;
        #pragma unroll
        for (int off = 16; off > 0; off >>= 1) ss += __shfl_xor(ss, off, 32);
        float e = x * (1.0f / sqrtf(ss));
        unsigned short hi = f2bf(e);
        unsigned short lo = f2bf(e - bf2f(hi));
        W[OFS_E_HI + row * VDIM + v] = hi;
        W[OFS_E_LO + row * VDIM + v] = lo;
        W[OFS_ET_HI + v * KCODES + row] = hi;
        W[OFS_ET_LO + v * KCODES + row] = lo;
        if (bid == 0 && tid == 0) loss_out[0] = 0.0f;
    } else if (bid < 640) {                // Wp split: 32*1024 elems
        int i = (bid - 512) * 256 + tid;
        float x = Wp[i];
        unsigned short hi = f2bf(x);
        W[OFS_WP_HI + i] = hi;
        W[OFS_WP_LO + i] = f2bf(x - bf2f(hi));
    } else {                               // Wpi split: 1024*32 elems
        int i = (bid - 640) * 256 + tid;
        float x = Wpi[i];
        unsigned short hi = f2bf(x);
        W[OFS_WPI_HI + i] = hi;
        W[OFS_WPI_LO + i] = f2bf(x - bf2f(hi));
    }
}

// ---------------------------------------------------------------------------
// k_proj: hp = h @ Wp^T + bp, L2-normalized, emitted as bf16 hi/lo splits.
// 512 blocks = one 16-token tile each; 4 waves = (v-half x k-half).
// Split-fp32 MFMA (4 products) keeps argmax-grade accuracy.
// ---------------------------------------------------------------------------
__global__ __launch_bounds__(256) void k_proj(const float* __restrict__ h,
                                              const unsigned short* __restrict__ W,
                                              const float* __restrict__ bp,
                                              unsigned short* __restrict__ hp_hi,
                                              unsigned short* __restrict__ hp_lo) {
    __shared__ float mrg[2][64][4];
    __shared__ float ssb[2][16];
    const unsigned short* Wp_hi = W + OFS_WP_HI;
    const unsigned short* Wp_lo = W + OFS_WP_LO;

    int tid = threadIdx.x;
    int w = tid >> 6, l = tid & 63, q = l >> 4, m = l & 15;
    int vh = w & 1, kh = w >> 1;
    int tok0 = blockIdx.x * 16;

    f32x4 acc = {0.f, 0.f, 0.f, 0.f};
    const float* hrow = h + (size_t)(tok0 + m) * DIM + kh * 512 + q * 8;
    const unsigned short* wph = Wp_hi + (size_t)(vh * 16 + m) * DIM + kh * 512 + q * 8;
    const unsigned short* wpl = Wp_lo + (size_t)(vh * 16 + m) * DIM + kh * 512 + q * 8;

    for (int s = 0; s < 16; ++s) {
        float4 a0 = *(const float4*)(hrow + s * 32);
        float4 a1 = *(const float4*)(hrow + s * 32 + 4);
        float va[8] = {a0.x, a0.y, a0.z, a0.w, a1.x, a1.y, a1.z, a1.w};
        short8 Ah, Al;
        #pragma unroll
        for (int j = 0; j < 8; ++j) {
            unsigned short hb = f2bf(va[j]);
            Ah[j] = (short)hb;
            Al[j] = (short)f2bf(va[j] - bf2f(hb));
        }
        short8 Bh = *(const short8*)(wph + s * 32);
        short8 Bl = *(const short8*)(wpl + s * 32);
        acc = MFMA16(Al, Bl, acc);
        acc = MFMA16(Al, Bh, acc);
        acc = MFMA16(Ah, Bl, acc);
        acc = MFMA16(Ah, Bh, acc);
    }
    if (kh == 1) {
        #pragma unroll
        for (int r = 0; r < 4; ++r) mrg[vh][l][r] = acc[r];
    }
    __syncthreads();
    float ss[4];
    if (kh == 0) {
        float b = bp[vh * 16 + m];
        #pragma unroll
        for (int r = 0; r < 4; ++r) {
            acc[r] += mrg[vh][l][r] + b;
            ss[r] = acc[r] * acc[r];
        }
        #pragma unroll
        for (int off = 1; off < 16; off <<= 1) {
            #pragma unroll
            for (int r = 0; r < 4; ++r) ss[r] += __shfl_xor(ss[r], off);
        }
        if (m == 0) {
            #pragma unroll
            for (int r = 0; r < 4; ++r) ssb[vh][q * 4 + r] = ss[r];
        }
    }
    __syncthreads();
    if (kh == 0) {
        #pragma unroll
        for (int r = 0; r < 4; ++r) {
            float tot = ss[r] + ssb[vh ^ 1][q * 4 + r];
            float val = acc[r] * (1.0f / sqrtf(tot));
            unsigned short hb = f2bf(val);
            size_t idx = (size_t)(tok0 + q * 4 + r) * VDIM + vh * 16 + m;
            hp_hi[idx] = hb;
            hp_lo[idx] = f2bf(val - bf2f(hb));
        }
    }
}

// ---------------------------------------------------------------------------
// k_vq_fused: scores (split MFMA, 4 products) -> exp -> argmax/l ->
// P@E^T (MFMA via per-wave LDS transpose of P) -> block merge -> normalize ->
// out = hv @ Wpi^T + bpi (MFMA). One 16-token tile per block; wave w owns
// code quarter [w*1024, w*1024+1024).
// Code tiles use even/odd interleave so each lane's two p-values are adjacent
// codes -> packed b32 LDS writes for the P transpose.
// ---------------------------------------------------------------------------
__global__ __launch_bounds__(256) void k_vq_fused(const unsigned short* __restrict__ W,
                                                  const float* __restrict__ mask,
                                                  const float* __restrict__ bpi,
                                                  float* __restrict__ out,
                                                  float* __restrict__ code_out) {
    __shared__ unsigned short pA_hi[4][16][40];  // 80B rows: 16B-aligned, 2-way banks (free)
    __shared__ unsigned short pA_lo[4][16][40];
    __shared__ float red_hv[4][16][33];
    __shared__ float red_l[4][16];
    __shared__ float red_am[4][16];
    __shared__ int   red_ai[4][16];
    __shared__ float invb[16];
    __shared__ unsigned short hvA_hi[16][40];
    __shared__ unsigned short hvA_lo[16][40];

    const unsigned short* E_hi  = W + OFS_E_HI;
    const unsigned short* E_lo  = W + OFS_E_LO;
    const unsigned short* Et_hi = W + OFS_ET_HI;
    const unsigned short* Et_lo = W + OFS_ET_LO;
    const unsigned short* Wpi_hi = W + OFS_WPI_HI;
    const unsigned short* Wpi_lo = W + OFS_WPI_LO;
    const unsigned short* hp_hi = W + OFS_HP_HI;
    const unsigned short* hp_lo = W + OFS_HP_LO;

    int tid = threadIdx.x;
    int w = tid >> 6, l = tid & 63, q = l >> 4, m = l & 15;
    int tok0 = blockIdx.x * 16;

    // A-frags for the score GEMM: hp row (token = tok0+m), k-offset q*8
    short8 ahi = *(const short8*)(hp_hi + (size_t)(tok0 + m) * VDIM + q * 8);
    short8 alo = *(const short8*)(hp_lo + (size_t)(tok0 + m) * VDIM + q * 8);

    const f32x4 zero4 = {0.f, 0.f, 0.f, 0.f};
    f32x4 hv0 = zero4, hv1 = zero4;
    float lr[4] = {0.f, 0.f, 0.f, 0.f};
    float am[4] = {-1e30f, -1e30f, -1e30f, -1e30f};
    int   ai[4] = {0, 0, 0, 0};

    for (int chunk = 0; chunk < 32; ++chunk) {
        int cb = w * 1024 + chunk * 32;
        // score B-frags: tile0 = even codes (cb+2m), tile1 = odd (cb+2m+1)
        size_t e0 = (size_t)(cb + 2 * m) * VDIM + q * 8;
        short8 b0h = *(const short8*)(E_hi + e0);
        short8 b0l = *(const short8*)(E_lo + e0);
        short8 b1h = *(const short8*)(E_hi + e0 + VDIM);
        short8 b1l = *(const short8*)(E_lo + e0 + VDIM);
        f32x4 s0 = MFMA16(alo, b0l, zero4);
        s0 = MFMA16(alo, b0h, s0);
        s0 = MFMA16(ahi, b0l, s0);
        s0 = MFMA16(ahi, b0h, s0);
        f32x4 s1 = MFMA16(alo, b1l, zero4);
        s1 = MFMA16(alo, b1h, s1);
        s1 = MFMA16(ahi, b1l, s1);
        s1 = MFMA16(ahi, b1h, s1);
        // elementwise: argmax, l, p = exp(2s), split + pack into LDS (A layout)
        #pragma unroll
        for (int r = 0; r < 4; ++r) {
            float sv0 = s0[r], sv1 = s1[r];
            int c0 = cb + 2 * m;
            if (sv0 > am[r]) { am[r] = sv0; ai[r] = c0; }
            if (sv1 > am[r]) { am[r] = sv1; ai[r] = c0 + 1; }
            float p0 = __expf(2.0f * sv0);
            float p1 = __expf(2.0f * sv1);
            lr[r] += p0 + p1;
            unsigned short h0 = f2bf(p0), h1 = f2bf(p1);
            unsigned short g0 = f2bf(p0 - bf2f(h0)), g1 = f2bf(p1 - bf2f(h1));
            int t = q * 4 + r;
            *(unsigned*)&pA_hi[w][t][2 * m] = (unsigned)h0 | ((unsigned)h1 << 16);
            *(unsigned*)&pA_lo[w][t][2 * m] = (unsigned)g0 | ((unsigned)g1 << 16);
        }
        // P as A-operand (per-wave LDS region: no barrier needed, wave-ordered)
        short8 pah = *(const short8*)&pA_hi[w][m][q * 8];
        short8 pal = *(const short8*)&pA_lo[w][m][q * 8];
        // Et B-frags (k = codes, n = v)
        short8 t0h = *(const short8*)(Et_hi + (size_t)m * KCODES + cb + q * 8);
        short8 t0l = *(const short8*)(Et_lo + (size_t)m * KCODES + cb + q * 8);
        short8 t1h = *(const short8*)(Et_hi + (size_t)(16 + m) * KCODES + cb + q * 8);
        short8 t1l = *(const short8*)(Et_lo + (size_t)(16 + m) * KCODES + cb + q * 8);
        hv0 = MFMA16(pal, t0h, hv0);
        hv0 = MFMA16(pah, t0l, hv0);
        hv0 = MFMA16(pah, t0h, hv0);
        hv1 = MFMA16(pal, t1h, hv1);
        hv1 = MFMA16(pah, t1l, hv1);
        hv1 = MFMA16(pah, t1h, hv1);
    }

    // reduce l/argmax across the 16 lanes sharing a quad (token group)
    #pragma unroll
    for (int off = 1; off < 16; off <<= 1) {
        #pragma unroll
        for (int r = 0; r < 4; ++r) {
            lr[r] += __shfl_xor(lr[r], off);
            float a2 = __shfl_xor(am[r], off);
            int   i2 = __shfl_xor(ai[r], off);
            if (a2 > am[r] || (a2 == am[r] && i2 < ai[r])) { am[r] = a2; ai[r] = i2; }
        }
    }
    if (m == 0) {
        #pragma unroll
        for (int r = 0; r < 4; ++r) {
            red_l[w][q * 4 + r]  = lr[r];
            red_am[w][q * 4 + r] = am[r];
            red_ai[w][q * 4 + r] = ai[r];
        }
    }
    #pragma unroll
    for (int r = 0; r < 4; ++r) {
        red_hv[w][q * 4 + r][m]      = hv0[r];
        red_hv[w][q * 4 + r][16 + m] = hv1[r];
    }
    __syncthreads();
    if (tid < 16) {
        int t = tid;
        float L = 0.f, A = -1e30f; int I = 0x7fffffff;
        #pragma unroll
        for (int ww = 0; ww < 4; ++ww) {
            L += red_l[ww][t];
            float a2 = red_am[ww][t]; int i2 = red_ai[ww][t];
            if (a2 > A || (a2 == A && i2 < I)) { A = a2; I = i2; }
        }
        bool on = (mask[tok0 + t] == 1.0f);
        code_out[tok0 + t] = on ? (float)I : 0.0f;
        invb[t] = on ? (1.0f / L) : 0.0f;
    }
    __syncthreads();
    {   // finalize hv, split to bf16 hi/lo in A-operand LDS layout
        int t = tid >> 4, pm = tid & 15;
        int v0 = 2 * pm;
        float x0 = (red_hv[0][t][v0] + red_hv[1][t][v0] +
                    red_hv[2][t][v0] + red_hv[3][t][v0]) * invb[t];
        float x1 = (red_hv[0][t][v0 + 1] + red_hv[1][t][v0 + 1] +
                    red_hv[2][t][v0 + 1] + red_hv[3][t][v0 + 1]) * invb[t];
        unsigned short h0 = f2bf(x0), h1 = f2bf(x1);
        unsigned short g0 = f2bf(x0 - bf2f(h0)), g1 = f2bf(x1 - bf2f(h1));
        *(unsigned*)&hvA_hi[t][v0] = (unsigned)h0 | ((unsigned)h1 << 16);
        *(unsigned*)&hvA_lo[t][v0] = (unsigned)g0 | ((unsigned)g1 << 16);
    }
    __syncthreads();
    // out-GEMM: wave w covers d in [w*256, w*256+256)
    short8 ah = *(const short8*)&hvA_hi[m][q * 8];
    short8 al = *(const short8*)&hvA_lo[m][q * 8];
    for (int dt = 0; dt < 16; ++dt) {
        int dbase = w * 256 + dt * 16;
        short8 wh = *(const short8*)(Wpi_hi + (size_t)(dbase + m) * VDIM + q * 8);
        short8 wl = *(const short8*)(Wpi_lo + (size_t)(dbase + m) * VDIM + q * 8);
        f32x4 o = MFMA16(al, wh, zero4);
        o = MFMA16(ah, wl, o);
        o = MFMA16(ah, wh, o);
        float bias = bpi[dbase + m];
        #pragma unroll
        for (int r = 0; r < 4; ++r)
            out[(size_t)(tok0 + q * 4 + r) * DIM + dbase + m] = o[r] + bias;
    }
}

// ---------------------------------------------------------------------------
extern "C" void kernel_launch(void* const* d_in, const int* in_sizes, int n_in,
                              void* d_out, int out_size, void* d_ws, size_t ws_size,
                              hipStream_t stream) {
    const float* h    = (const float*)d_in[0];
    const float* mask = (const float*)d_in[1];
    const float* Wp   = (const float*)d_in[2];
    const float* bp   = (const float*)d_in[3];
    const float* Wpi  = (const float*)d_in[4];
    const float* bpi  = (const float*)d_in[5];
    const float* emb  = (const float*)d_in[6];
    float* out = (float*)d_out;

    unsigned short* W = (unsigned short*)d_ws;
    unsigned short* hp_hi = W + OFS_HP_HI;
    unsigned short* hp_lo = W + OFS_HP_LO;

    float* code_out = out + (size_t)NTOK * DIM;
    float* loss_out = code_out + NTOK;

    hipLaunchKernelGGL(k_prep,     dim3(768), dim3(256), 0, stream, emb, Wp, Wpi, W, loss_out);
    hipLaunchKernelGGL(k_proj,     dim3(512), dim3(256), 0, stream, h, W, bp, hp_hi, hp_lo);
    hipLaunchKernelGGL(k_vq_fused, dim3(512), dim3(256), 0, stream, W, mask, bpi, out, code_out);
}

// Round 3
// 138.402 us; speedup vs baseline: 1.7256x; 1.2524x over previous
//
#include <hip/hip_runtime.h>
#include <hip/hip_bf16.h>
#include <math.h>

#define NTOK 8192     // B*L
#define DIM  1024     // D
#define VDIM 32       // V
#define KCODES 4096   // K

typedef __attribute__((ext_vector_type(8))) short short8;
typedef __attribute__((ext_vector_type(4))) float f32x4;

// MFMA16(A,B,C): D[row=4q+r <- A's m-dim][col=m <- B's n-dim]; A-frag lane(q,m)
// holds A[m][k=q*8+j], B-frag lane(q,m) holds B[n=m][k=q*8+j]. (verified vs R2)
#define MFMA16(A,B,C) __builtin_amdgcn_mfma_f32_16x16x32_bf16(A, B, C, 0, 0, 0)

__device__ __forceinline__ unsigned short f2bf(float x) {
    unsigned u = __builtin_bit_cast(unsigned, x);
    u += 0x7FFF + ((u >> 16) & 1);              // RTNE (finite inputs only)
    return (unsigned short)(u >> 16);
}
__device__ __forceinline__ float bf2f(unsigned short b) {
    unsigned u = ((unsigned)b) << 16;
    return __builtin_bit_cast(float, u);
}

struct U4 { unsigned x, y, z, w; };

// split 8 fp32 -> bf16 hi/lo fragments (element j of frag = p[j])
__device__ __forceinline__ void split8(const float* p, short8* H, short8* L) {
    unsigned hh[4], ll[4];
    #pragma unroll
    for (int i = 0; i < 4; ++i) {
        unsigned short a = f2bf(p[2 * i]);
        unsigned short b = f2bf(p[2 * i + 1]);
        hh[i] = (unsigned)a | ((unsigned)b << 16);
        unsigned short la = f2bf(p[2 * i] - bf2f(a));
        unsigned short lb = f2bf(p[2 * i + 1] - bf2f(b));
        ll[i] = (unsigned)la | ((unsigned)lb << 16);
    }
    U4 uh = {hh[0], hh[1], hh[2], hh[3]};
    U4 ul = {ll[0], ll[1], ll[2], ll[3]};
    *H = __builtin_bit_cast(short8, uh);
    *L = __builtin_bit_cast(short8, ul);
}

// ---------------------------------------------------------------------------
// ws layout (u16 units)
// ---------------------------------------------------------------------------
#define OFS_E_HI   0          // E  [4096][32]
#define OFS_E_LO   131072
#define OFS_ET_HI  262144     // Et [32][4096]
#define OFS_ET_LO  393216
#define OFS_WP_HI  524288     // Wp [32][1024]
#define OFS_WP_LO  557056
#define OFS_WPI_HI 589824     // Wpi [1024][32]
#define OFS_WPI_LO 622592

// ---------------------------------------------------------------------------
// k_prep: normalize emb -> E hi/lo (row-major) + Et hi/lo (coalesced via LDS
// transpose); split Wp/Wpi into bf16 hi/lo; vq_loss = 0.
// ---------------------------------------------------------------------------
__global__ __launch_bounds__(256) void k_prep(const float* __restrict__ emb,
                                              const float* __restrict__ Wp,
                                              const float* __restrict__ Wpi,
                                              unsigned short* __restrict__ W,
                                              float* __restrict__ loss_out) {
    __shared__ __align__(16) unsigned short Th[32][72];
    __shared__ __align__(16) unsigned short Tl[32][72];
    int bid = blockIdx.x, tid = threadIdx.x;
    if (bid < 64) {                       // 64 codes per block
        int cb = bid * 64;
        int c = tid >> 2, s = tid & 3;    // code-local, v-quarter
        const float* src = emb + (size_t)(cb + c) * VDIM + s * 8;
        float4 a = *(const float4*)src;
        float4 b = *(const float4*)(src + 4);
        float ps = a.x*a.x + a.y*a.y + a.z*a.z + a.w*a.w
                 + b.x*b.x + b.y*b.y + b.z*b.z + b.w*b.w;
        ps += __shfl_xor(ps, 1);
        ps += __shfl_xor(ps, 2);
        float inv = 1.0f / sqrtf(ps);
        float vals[8] = {a.x*inv, a.y*inv, a.z*inv, a.w*inv,
                         b.x*inv, b.y*inv, b.z*inv, b.w*inv};
        short8 H, L;
        split8(vals, &H, &L);
        *(short8*)(W + OFS_E_HI + (size_t)(cb + c) * VDIM + s * 8) = H;
        *(short8*)(W + OFS_E_LO + (size_t)(cb + c) * VDIM + s * 8) = L;
        #pragma unroll
        for (int j = 0; j < 8; ++j) {
            unsigned short hb = f2bf(vals[j]);
            Th[s * 8 + j][c] = hb;
            Tl[s * 8 + j][c] = f2bf(vals[j] - bf2f(hb));
        }
        __syncthreads();
        int row = tid >> 3, seg = tid & 7;
        *(short8*)(W + OFS_ET_HI + (size_t)row * KCODES + cb + seg * 8) =
            *(const short8*)&Th[row][seg * 8];
        *(short8*)(W + OFS_ET_LO + (size_t)row * KCODES + cb + seg * 8) =
            *(const short8*)&Tl[row][seg * 8];
        if (bid == 0 && tid == 0) loss_out[0] = 0.0f;
    } else if (bid < 80) {                // Wp split: 16 blocks x 2048
        int i0 = (bid - 64) * 2048 + tid * 8;
        float4 a = *(const float4*)(Wp + i0);
        float4 b = *(const float4*)(Wp + i0 + 4);
        float vals[8] = {a.x, a.y, a.z, a.w, b.x, b.y, b.z, b.w};
        short8 H, L;
        split8(vals, &H, &L);
        *(short8*)(W + OFS_WP_HI + i0) = H;
        *(short8*)(W + OFS_WP_LO + i0) = L;
    } else {                              // Wpi split: 16 blocks x 2048
        int i0 = (bid - 80) * 2048 + tid * 8;
        float4 a = *(const float4*)(Wpi + i0);
        float4 b = *(const float4*)(Wpi + i0 + 4);
        float vals[8] = {a.x, a.y, a.z, a.w, b.x, b.y, b.z, b.w};
        short8 H, L;
        split8(vals, &H, &L);
        *(short8*)(W + OFS_WPI_HI + i0) = H;
        *(short8*)(W + OFS_WPI_LO + i0) = L;
    }
}

// ---------------------------------------------------------------------------
// k_fused: proj+normalize -> scores -> softmax/argmax -> P@E^T -> out-GEMM.
// 256 blocks x 1024 threads (16 waves). 32 tokens/block.
// All GEMMs transposed (D rows = non-token dim, cols = tokens) with sigma-
// permuted A-rows so softmax output feeds PV — and hv feeds out-GEMM —
// entirely in-register (no per-chunk LDS).
// ---------------------------------------------------------------------------
__global__ __launch_bounds__(1024) void k_fused(const float* __restrict__ h,
                                                const float* __restrict__ mask,
                                                const unsigned short* __restrict__ W,
                                                const float* __restrict__ bp,
                                                const float* __restrict__ bpi,
                                                float* __restrict__ out,
                                                float* __restrict__ code_out) {
    __shared__ __align__(16) float red2[8][32][36];          // 36.9 KB merge buffer
    __shared__ __align__(16) unsigned short hpB_hi[32][40];
    __shared__ __align__(16) unsigned short hpB_lo[32][40];
    __shared__ __align__(16) unsigned short hvB_hi[32][40];
    __shared__ __align__(16) unsigned short hvB_lo[32][40];
    __shared__ float lred[16][33];
    __shared__ float amred[16][33];
    __shared__ int   aired[16][33];
    __shared__ float invl[32];

    const unsigned short* E_hi   = W + OFS_E_HI;
    const unsigned short* E_lo   = W + OFS_E_LO;
    const unsigned short* Et_hi  = W + OFS_ET_HI;
    const unsigned short* Et_lo  = W + OFS_ET_LO;
    const unsigned short* Wp_hi  = W + OFS_WP_HI;
    const unsigned short* Wp_lo  = W + OFS_WP_LO;
    const unsigned short* Wpi_hi = W + OFS_WPI_HI;
    const unsigned short* Wpi_lo = W + OFS_WPI_LO;

    int tid = threadIdx.x;
    int w = tid >> 6;
    int l = tid & 63;
    int q = l >> 4, m = l & 15;
    int tok0 = blockIdx.x * 32;
    int sig = ((m & 12) << 1) | (m & 3);     // sigma0(m) = 8*(m>>2) + (m&3)
    const f32x4 zero4 = {0.f, 0.f, 0.f, 0.f};

    // ================= Phase 1: hp = h @ Wp^T + bp, L2-normalize =============
    {
        int tt = w >> 3, kw = w & 7;          // token-half, k-slice (128 wide)
        f32x4 acc0 = zero4, acc1 = zero4;     // v-tiles 0..15, 16..31
        const float* hb = h + (size_t)(tok0 + tt * 16 + m) * DIM + kw * 128 + q * 8;
        const unsigned short* w0h = Wp_hi + (size_t)m * DIM + kw * 128 + q * 8;
        const unsigned short* w0l = Wp_lo + (size_t)m * DIM + kw * 128 + q * 8;
        const unsigned short* w1h = w0h + (size_t)16 * DIM;
        const unsigned short* w1l = w0l + (size_t)16 * DIM;
        #pragma unroll
        for (int c = 0; c < 4; ++c) {
            float4 a = *(const float4*)(hb + c * 32);
            float4 b = *(const float4*)(hb + c * 32 + 4);
            float va[8] = {a.x, a.y, a.z, a.w, b.x, b.y, b.z, b.w};
            short8 Bh, Bl;
            split8(va, &Bh, &Bl);
            short8 A0h = *(const short8*)(w0h + c * 32);
            short8 A0l = *(const short8*)(w0l + c * 32);
            short8 A1h = *(const short8*)(w1h + c * 32);
            short8 A1l = *(const short8*)(w1l + c * 32);
            acc0 = MFMA16(A0l, Bl, acc0); acc0 = MFMA16(A0l, Bh, acc0);
            acc0 = MFMA16(A0h, Bl, acc0); acc0 = MFMA16(A0h, Bh, acc0);
            acc1 = MFMA16(A1l, Bl, acc1); acc1 = MFMA16(A1l, Bh, acc1);
            acc1 = MFMA16(A1h, Bl, acc1); acc1 = MFMA16(A1h, Bh, acc1);
        }
        // D: lane(q,m) reg r -> hp_partial[v = vt*16+4q+r][t = tt*16+m]
        int slot = tt * 4 + (kw & 3);
        if ((kw & 4) == 0) {
            *(f32x4*)&red2[slot][m][4 * q]      = acc0;
            *(f32x4*)&red2[slot][m][16 + 4 * q] = acc1;
        }
        __syncthreads();
        if (kw & 4) {
            f32x4* d0 = (f32x4*)&red2[slot][m][4 * q];
            f32x4* d1 = (f32x4*)&red2[slot][m][16 + 4 * q];
            *d0 = *d0 + acc0;
            *d1 = *d1 + acc1;
        }
        __syncthreads();
    }
    {   // merge + bias + normalize -> hpB (bf16 hi/lo in LDS)
        int t = tid >> 5, v = tid & 31;
        int sb = (t >> 4) * 4, tr = t & 15;
        float s = bp[v];
        #pragma unroll
        for (int j = 0; j < 4; ++j) s += red2[sb + j][tr][v];
        float sq = s * s;
        #pragma unroll
        for (int off = 1; off < 32; off <<= 1) sq += __shfl_xor(sq, off);
        float nv = s * (1.0f / sqrtf(sq));
        unsigned short hb = f2bf(nv);
        hpB_hi[t][v] = hb;
        hpB_lo[t][v] = f2bf(nv - bf2f(hb));
    }
    __syncthreads();

    // ================= Phase 2: scores -> softmax -> P@E^T ===================
    short8 hp0h = *(const short8*)&hpB_hi[m][q * 8];
    short8 hp0l = *(const short8*)&hpB_lo[m][q * 8];
    short8 hp1h = *(const short8*)&hpB_hi[16 + m][q * 8];
    short8 hp1l = *(const short8*)&hpB_lo[16 + m][q * 8];

    f32x4 hv00 = zero4, hv01 = zero4, hv10 = zero4, hv11 = zero4; // [tt][vt]
    float ls0 = 0.f, ls1 = 0.f;
    float am0 = -1e30f, am1 = -1e30f;
    int ai0 = 0, ai1 = 0;

    #pragma unroll 1
    for (int c = 0; c < 8; ++c) {
        int cb = w * 256 + c * 32;
        // score A-frags: permuted code rows (tile0: cb+sig, tile1: cb+sig+4)
        size_t e0 = (size_t)(cb + sig) * VDIM + q * 8;
        short8 E0h = *(const short8*)(E_hi + e0);
        short8 E0l = *(const short8*)(E_lo + e0);
        short8 E1h = *(const short8*)(E_hi + e0 + 4 * VDIM);
        short8 E1l = *(const short8*)(E_lo + e0 + 4 * VDIM);
        // PV A-frags: permuted v rows of Et (vt0: sig, vt1: sig+4)
        size_t t0 = (size_t)sig * KCODES + cb + q * 8;
        short8 T0h = *(const short8*)(Et_hi + t0);
        short8 T0l = *(const short8*)(Et_lo + t0);
        short8 T1h = *(const short8*)(Et_hi + t0 + (size_t)4 * KCODES);
        short8 T1l = *(const short8*)(Et_lo + t0 + (size_t)4 * KCODES);

        // ---- token-half 0 ----
        {
            f32x4 s0 = MFMA16(E0l, hp0l, zero4);
            s0 = MFMA16(E0l, hp0h, s0);
            s0 = MFMA16(E0h, hp0l, s0);
            s0 = MFMA16(E0h, hp0h, s0);
            f32x4 s1 = MFMA16(E1l, hp0l, zero4);
            s1 = MFMA16(E1l, hp0h, s1);
            s1 = MFMA16(E1h, hp0l, s1);
            s1 = MFMA16(E1h, hp0h, s1);
            float p[8];
            #pragma unroll
            for (int r = 0; r < 4; ++r) {
                float sv = s0[r];
                if (sv > am0) { am0 = sv; ai0 = cb + 8 * q + r; }
                p[r] = __expf(2.0f * sv);
                sv = s1[r];
                if (sv > am0) { am0 = sv; ai0 = cb + 8 * q + 4 + r; }
                p[4 + r] = __expf(2.0f * sv);
            }
            ls0 += ((p[0] + p[1]) + (p[2] + p[3])) + ((p[4] + p[5]) + (p[6] + p[7]));
            short8 Ph, Pl;
            split8(p, &Ph, &Pl);
            hv00 = MFMA16(T0l, Ph, hv00);
            hv00 = MFMA16(T0h, Pl, hv00);
            hv00 = MFMA16(T0h, Ph, hv00);
            hv01 = MFMA16(T1l, Ph, hv01);
            hv01 = MFMA16(T1h, Pl, hv01);
            hv01 = MFMA16(T1h, Ph, hv01);
        }
        // ---- token-half 1 ----
        {
            f32x4 s0 = MFMA16(E0l, hp1l, zero4);
            s0 = MFMA16(E0l, hp1h, s0);
            s0 = MFMA16(E0h, hp1l, s0);
            s0 = MFMA16(E0h, hp1h, s0);
            f32x4 s1 = MFMA16(E1l, hp1l, zero4);
            s1 = MFMA16(E1l, hp1h, s1);
            s1 = MFMA16(E1h, hp1l, s1);
            s1 = MFMA16(E1h, hp1h, s1);
            float p[8];
            #pragma unroll
            for (int r = 0; r < 4; ++r) {
                float sv = s0[r];
                if (sv > am1) { am1 = sv; ai1 = cb + 8 * q + r; }
                p[r] = __expf(2.0f * sv);
                sv = s1[r];
                if (sv > am1) { am1 = sv; ai1 = cb + 8 * q + 4 + r; }
                p[4 + r] = __expf(2.0f * sv);
            }
            ls1 += ((p[0] + p[1]) + (p[2] + p[3])) + ((p[4] + p[5]) + (p[6] + p[7]));
            short8 Ph, Pl;
            split8(p, &Ph, &Pl);
            hv10 = MFMA16(T0l, Ph, hv10);
            hv10 = MFMA16(T0h, Pl, hv10);
            hv10 = MFMA16(T0h, Ph, hv10);
            hv11 = MFMA16(T1l, Ph, hv11);
            hv11 = MFMA16(T1h, Pl, hv11);
            hv11 = MFMA16(T1h, Ph, hv11);
        }
    }

    // cross-q reduction (lanes ^16, ^32 share token column m)
    #pragma unroll
    for (int off = 16; off <= 32; off <<= 1) {
        ls0 += __shfl_xor(ls0, off);
        ls1 += __shfl_xor(ls1, off);
        float a2 = __shfl_xor(am0, off);
        int   i2 = __shfl_xor(ai0, off);
        if (a2 > am0 || (a2 == am0 && i2 < ai0)) { am0 = a2; ai0 = i2; }
        a2 = __shfl_xor(am1, off);
        i2 = __shfl_xor(ai1, off);
        if (a2 > am1 || (a2 == am1 && i2 < ai1)) { am1 = a2; ai1 = i2; }
    }
    if (q == 0) {
        lred[w][m] = ls0;       amred[w][m] = am0;       aired[w][m] = ai0;
        lred[w][16 + m] = ls1;  amred[w][16 + m] = am1;  aired[w][16 + m] = ai1;
    }
    // hv partials -> red2 (deterministic 2-stage store/add)
    // D2: lane(q,m) reg r -> hv_partial[v = 8q+4vt+r][t = tt*16+m]
    if (w < 8) {
        *(f32x4*)&red2[w][m][8 * q]          = hv00;
        *(f32x4*)&red2[w][m][8 * q + 4]      = hv01;
        *(f32x4*)&red2[w][16 + m][8 * q]     = hv10;
        *(f32x4*)&red2[w][16 + m][8 * q + 4] = hv11;
    }
    __syncthreads();
    if (w >= 8) {
        f32x4* d;
        d = (f32x4*)&red2[w - 8][m][8 * q];          *d = *d + hv00;
        d = (f32x4*)&red2[w - 8][m][8 * q + 4];      *d = *d + hv01;
        d = (f32x4*)&red2[w - 8][16 + m][8 * q];     *d = *d + hv10;
        d = (f32x4*)&red2[w - 8][16 + m][8 * q + 4]; *d = *d + hv11;
    }
    __syncthreads();
    if (tid < 32) {
        float L = 0.f, A = -1e30f;
        int I = 0x7fffffff;
        #pragma unroll
        for (int ww = 0; ww < 16; ++ww) {
            L += lred[ww][tid];
            float a2 = amred[ww][tid];
            int   i2 = aired[ww][tid];
            if (a2 > A || (a2 == A && i2 < I)) { A = a2; I = i2; }
        }
        bool on = (mask[tok0 + tid] == 1.0f);
        code_out[tok0 + tid] = on ? (float)I : 0.0f;
        invl[tid] = on ? (1.0f / L) : 0.0f;
    }
    __syncthreads();
    {   // finalize hv -> bf16 hi/lo in LDS
        int t = tid >> 5, v = tid & 31;
        float x = 0.f;
        #pragma unroll
        for (int s = 0; s < 8; ++s) x += red2[s][t][v];
        x *= invl[t];
        unsigned short hb = f2bf(x);
        hvB_hi[t][v] = hb;
        hvB_lo[t][v] = f2bf(x - bf2f(hb));
    }
    __syncthreads();

    // ================= Phase 3: out = hv @ Wpi^T + bpi =======================
    short8 g0h = *(const short8*)&hvB_hi[m][q * 8];
    short8 g0l = *(const short8*)&hvB_lo[m][q * 8];
    short8 g1h = *(const short8*)&hvB_hi[16 + m][q * 8];
    short8 g1l = *(const short8*)&hvB_lo[16 + m][q * 8];
    #pragma unroll
    for (int dt = 0; dt < 4; ++dt) {
        int dbase = w * 64 + dt * 16;
        short8 Ah = *(const short8*)(Wpi_hi + (size_t)(dbase + m) * VDIM + q * 8);
        short8 Al = *(const short8*)(Wpi_lo + (size_t)(dbase + m) * VDIM + q * 8);
        f32x4 o0 = MFMA16(Al, g0h, zero4);
        o0 = MFMA16(Ah, g0l, o0);
        o0 = MFMA16(Ah, g0h, o0);
        f32x4 o1 = MFMA16(Al, g1h, zero4);
        o1 = MFMA16(Ah, g1l, o1);
        o1 = MFMA16(Ah, g1h, o1);
        float4 bias = *(const float4*)(bpi + dbase + 4 * q);
        // D3: lane(q,m) reg r -> out^T[d = dbase+4q+r][t = tt*16+m]
        float4 r0 = make_float4(o0[0] + bias.x, o0[1] + bias.y,
                                o0[2] + bias.z, o0[3] + bias.w);
        float4 r1 = make_float4(o1[0] + bias.x, o1[1] + bias.y,
                                o1[2] + bias.z, o1[3] + bias.w);
        *(float4*)(out + (size_t)(tok0 + m) * DIM + dbase + 4 * q) = r0;
        *(float4*)(out + (size_t)(tok0 + 16 + m) * DIM + dbase + 4 * q) = r1;
    }
}

// ---------------------------------------------------------------------------
extern "C" void kernel_launch(void* const* d_in, const int* in_sizes, int n_in,
                              void* d_out, int out_size, void* d_ws, size_t ws_size,
                              hipStream_t stream) {
    const float* h    = (const float*)d_in[0];
    const float* mask = (const float*)d_in[1];
    const float* Wp   = (const float*)d_in[2];
    const float* bp   = (const float*)d_in[3];
    const float* Wpi  = (const float*)d_in[4];
    const float* bpi  = (const float*)d_in[5];
    const float* emb  = (const float*)d_in[6];
    float* out = (float*)d_out;

    unsigned short* W = (unsigned short*)d_ws;
    float* code_out = out + (size_t)NTOK * DIM;
    float* loss_out = code_out + NTOK;

    hipLaunchKernelGGL(k_prep,  dim3(96),  dim3(256),  0, stream, emb, Wp, Wpi, W, loss_out);
    hipLaunchKernelGGL(k_fused, dim3(256), dim3(1024), 0, stream, h, mask, W, bp, bpi, out, code_out);
}